// Round 1
// baseline (368.501 us; speedup 1.0000x reference)
//
#include <hip/hip_runtime.h>
#include <hip/hip_bf16.h>

// Problem constants (match reference)
#define BATCH 32
#define NDIM  1024
#define NSEG  (NDIM - 1)       // 1023 segments
#define GROUPS 32              // row-groups per batch
#define BLK   256

// ---------------------------------------------------------------------------
// Kernel 0: zero the workspace accumulators (d_ws is poisoned 0xAA).
// ---------------------------------------------------------------------------
__global__ void zero_ws_kernel(float* p, int n) {
    int i = blockIdx.x * blockDim.x + threadIdx.x;
    if (i < n) p[i] = 0.0f;
}

// ---------------------------------------------------------------------------
// Kernel 1: per-(batch,row-group) partial segment sums via LDS bins.
// Row-major coalesced reads; scatter into LDS with ds_add_f32.
// Within a row, all lanes hit distinct consecutive segments (s = j-i-1),
// so LDS atomics have no same-address contention and stride-1 banks.
// ---------------------------------------------------------------------------
__global__ __launch_bounds__(BLK) void seg_partial_kernel(
        const float* __restrict__ S,   // (BATCH, NDIM, NDIM)
        float* __restrict__ gsum,      // (BATCH, NSEG)
        float* __restrict__ gsq)       // (BATCH, NSEG)
{
    const int b  = blockIdx.x / GROUPS;
    const int g0 = blockIdx.x % GROUPS;

    __shared__ float lsum[NSEG];
    __shared__ float lsq[NSEG];
    for (int t = threadIdx.x; t < NSEG; t += BLK) {
        lsum[t] = 0.0f;
        lsq[t]  = 0.0f;
    }
    __syncthreads();

    const float* Sb = S + (size_t)b * NDIM * NDIM;

    // Round-robin rows: i = g0, g0+GROUPS, ...  balances triangle row lengths.
    for (int i = g0; i < NDIM - 1; i += GROUPS) {
        const float* row = Sb + (size_t)i * NDIM;
        for (int j = i + 1 + threadIdx.x; j < NDIM; j += BLK) {
            float v = row[j];
            int s = j - i - 1;
            atomicAdd(&lsum[s], v);
            atomicAdd(&lsq[s], v * v);
        }
    }
    __syncthreads();

    float* gs = gsum + (size_t)b * NSEG;
    float* gq = gsq  + (size_t)b * NSEG;
    for (int t = threadIdx.x; t < NSEG; t += BLK) {
        atomicAdd(&gs[t], lsum[t]);
        atomicAdd(&gq[t], lsq[t]);
    }
}

// ---------------------------------------------------------------------------
// Kernel 2: finalize. One block; each thread handles a strided subset of the
// BATCH*(NSEG-1) (b,s) cells, computes std_scaled, block-reduces, writes mean.
// per_sample mean over segments then mean over batch == grand mean (equal
// counts per batch).
// ---------------------------------------------------------------------------
__global__ __launch_bounds__(BLK) void finalize_kernel(
        const float* __restrict__ gsum,
        const float* __restrict__ gsq,
        float* __restrict__ out)
{
    const int NUSE = NSEG - 1;          // 1022 segments used
    const int TOT  = BATCH * NUSE;

    float acc = 0.0f;
    for (int idx = threadIdx.x; idx < TOT; idx += BLK) {
        int b = idx / NUSE;
        int s = idx % NUSE;
        float cnt  = (float)(NDIM - 1 - s);
        float sum  = gsum[(size_t)b * NSEG + s];
        float sq   = gsq [(size_t)b * NSEG + s];
        float mean = sum / cnt;
        float var  = (sq - cnt * mean * mean) / (cnt - 1.0f);
        float stds = sqrtf(fmaxf(var, 0.0f)) * cnt * 0.05f;   // * cnt / 20
        acc += stds;
    }

    // wave64 reduce
    #pragma unroll
    for (int off = 32; off > 0; off >>= 1)
        acc += __shfl_down(acc, off, 64);

    __shared__ float wpart[BLK / 64];
    int lane = threadIdx.x & 63;
    int w    = threadIdx.x >> 6;
    if (lane == 0) wpart[w] = acc;
    __syncthreads();
    if (threadIdx.x == 0) {
        float t = 0.0f;
        #pragma unroll
        for (int k = 0; k < BLK / 64; ++k) t += wpart[k];
        out[0] = t / (float)TOT;
    }
}

// ---------------------------------------------------------------------------
extern "C" void kernel_launch(void* const* d_in, const int* in_sizes, int n_in,
                              void* d_out, int out_size, void* d_ws, size_t ws_size,
                              hipStream_t stream) {
    const float* S = (const float*)d_in[0];
    float* out = (float*)d_out;

    float* gsum = (float*)d_ws;                   // BATCH*NSEG floats
    float* gsq  = gsum + (size_t)BATCH * NSEG;    // BATCH*NSEG floats
    const int nacc = 2 * BATCH * NSEG;            // 65472 floats (262 KB)

    zero_ws_kernel<<<(nacc + BLK - 1) / BLK, BLK, 0, stream>>>(gsum, nacc);
    seg_partial_kernel<<<BATCH * GROUPS, BLK, 0, stream>>>(S, gsum, gsq);
    finalize_kernel<<<1, BLK, 0, stream>>>(gsum, gsq, out);
}

// Round 2
// 236.665 us; speedup vs baseline: 1.5571x; 1.5571x over previous
//
#include <hip/hip_runtime.h>
#include <hip/hip_bf16.h>

// Problem constants (match reference)
#define BATCH 32
#define NDIM  1024
#define NSEGP 1024          // padded segment slots per partial (1023 real)
#define NUSE  1022          // segments used in the mean (nseg - 1)
#define BLK   256

// ---------------------------------------------------------------------------
// Kernel 1: register-binned partial segment sums. Thread t owns segments
// {t, t+256, t+512, t+768}. For row i it reads columns j = i+1+t+256k —
// consecutive lanes -> consecutive addresses (coalesced dword loads), 4
// independent loads per row for ILP. NO atomics, NO LDS in the hot loop.
// Each block writes its own (sum, sq) partial vector to a private ws slot.
// ---------------------------------------------------------------------------
__global__ __launch_bounds__(BLK) void seg_partial_kernel(
        const float* __restrict__ S,     // (BATCH, NDIM, NDIM)
        float* __restrict__ part,        // (BATCH*G, 2, NSEGP)
        int G)
{
    const int b = blockIdx.x / G;
    const int g = blockIdx.x % G;
    const int t = threadIdx.x;

    float s0 = 0.f, s1 = 0.f, s2 = 0.f, s3 = 0.f;
    float q0 = 0.f, q1 = 0.f, q2 = 0.f, q3 = 0.f;

    const float* Sb = S + (size_t)b * NDIM * NDIM;

    // Round-robin rows across the G groups to balance triangle row lengths.
    for (int i = g; i < NDIM - 1; i += G) {
        const float* row = Sb + (size_t)i * NDIM;
        const int j0 = i + 1 + t;
        if (j0 < NDIM)       { float v = row[j0];       s0 += v; q0 += v * v; }
        if (j0 + 256 < NDIM) { float v = row[j0 + 256]; s1 += v; q1 += v * v; }
        if (j0 + 512 < NDIM) { float v = row[j0 + 512]; s2 += v; q2 += v * v; }
        if (j0 + 768 < NDIM) { float v = row[j0 + 768]; s3 += v; q3 += v * v; }
    }

    float* psum = part + (size_t)blockIdx.x * (2 * NSEGP);
    float* psq  = psum + NSEGP;
    psum[t]       = s0;  psum[t + 256] = s1;
    psum[t + 512] = s2;  psum[t + 768] = s3;
    psq[t]        = q0;  psq[t + 256]  = q1;
    psq[t + 512]  = q2;  psq[t + 768]  = q3;
}

// ---------------------------------------------------------------------------
// Kernel 2: one block per batch. Reduce the G group-partials per segment,
// compute std_scaled, mean over the first NUSE segments -> bmean[b].
// ---------------------------------------------------------------------------
__global__ __launch_bounds__(BLK) void reduce_kernel(
        const float* __restrict__ part,  // (BATCH*G, 2, NSEGP)
        float* __restrict__ bmean,       // (BATCH)
        int G)
{
    const int b = blockIdx.x;

    float acc = 0.f;
    for (int s = threadIdx.x; s < NUSE; s += BLK) {
        float sum = 0.f, sq = 0.f;
        const float* p = part + (size_t)b * G * (2 * NSEGP);
        for (int g = 0; g < G; ++g) {
            sum += p[s];
            sq  += p[NSEGP + s];
            p += 2 * NSEGP;
        }
        float cnt  = (float)(NDIM - 1 - s);
        float mean = sum / cnt;
        float var  = (sq - cnt * mean * mean) / (cnt - 1.0f);
        acc += sqrtf(fmaxf(var, 0.0f)) * cnt * 0.05f;   // * cnt / 20
    }

    #pragma unroll
    for (int off = 32; off > 0; off >>= 1)
        acc += __shfl_down(acc, off, 64);

    __shared__ float wpart[BLK / 64];
    if ((threadIdx.x & 63) == 0) wpart[threadIdx.x >> 6] = acc;
    __syncthreads();
    if (threadIdx.x == 0) {
        float tsum = 0.f;
        #pragma unroll
        for (int k = 0; k < BLK / 64; ++k) tsum += wpart[k];
        bmean[b] = tsum / (float)NUSE;
    }
}

// ---------------------------------------------------------------------------
// Kernel 3: average the 32 per-batch means -> scalar output.
// ---------------------------------------------------------------------------
__global__ void final_kernel(const float* __restrict__ bmean,
                             float* __restrict__ out)
{
    float v = (threadIdx.x < BATCH) ? bmean[threadIdx.x] : 0.f;
    #pragma unroll
    for (int off = 32; off > 0; off >>= 1)
        v += __shfl_down(v, off, 64);
    if (threadIdx.x == 0) out[0] = v / (float)BATCH;
}

// ---------------------------------------------------------------------------
extern "C" void kernel_launch(void* const* d_in, const int* in_sizes, int n_in,
                              void* d_out, int out_size, void* d_ws, size_t ws_size,
                              hipStream_t stream) {
    const float* S = (const float*)d_in[0];
    float* out = (float*)d_out;

    // Pick the largest group count whose partial buffer fits the workspace.
    // (ws_size is fixed across calls, so G is deterministic -> graph-safe.)
    int G = 32;
    while (G > 1 &&
           (size_t)BATCH * G * 2 * NSEGP * sizeof(float) + BATCH * sizeof(float) > ws_size)
        G >>= 1;

    float* part  = (float*)d_ws;                         // BATCH*G*2*NSEGP floats
    float* bmean = part + (size_t)BATCH * G * 2 * NSEGP; // BATCH floats

    seg_partial_kernel<<<BATCH * G, BLK, 0, stream>>>(S, part, G);
    reduce_kernel<<<BATCH, BLK, 0, stream>>>(part, bmean, G);
    final_kernel<<<1, 64, 0, stream>>>(bmean, out);
}

// Round 3
// 219.676 us; speedup vs baseline: 1.6775x; 1.0773x over previous
//
#include <hip/hip_runtime.h>
#include <hip/hip_bf16.h>

// Problem constants (match reference)
#define BATCH 32
#define NDIM  1024
#define NSEGP 1024          // padded segment slots per partial (1023 real)
#define NUSE  1022          // segments used in the mean (nseg - 1)
#define BLK   256
#define G     32            // row-groups per batch (compile-time!)
#define CHUNKS 4            // segment chunks in reduce (4 * 256 = 1024 slots)

// ---------------------------------------------------------------------------
// Kernel 1: register-binned partial segment sums. Thread t owns segments
// {t, t+256, t+512, t+768} (s = j-i-1 with j = i+1+t+256k is invariant in i).
// Fully unrolled 32-row loop -> ~128 independent coalesced dword loads per
// thread for deep MLP (memory-level parallelism). No atomics, no LDS.
// ---------------------------------------------------------------------------
__global__ __launch_bounds__(BLK) void seg_partial_kernel(
        const float* __restrict__ S,     // (BATCH, NDIM, NDIM)
        float* __restrict__ part)        // (BATCH*G, 2, NSEGP)
{
    const int b = blockIdx.x >> 5;       // / G
    const int g = blockIdx.x & (G - 1);  // % G
    const int t = threadIdx.x;

    float s0 = 0.f, s1 = 0.f, s2 = 0.f, s3 = 0.f;
    float q0 = 0.f, q1 = 0.f, q2 = 0.f, q3 = 0.f;

    const float* Sb = S + (size_t)b * NDIM * NDIM;

    // Rows i = g, g+32, ..., g+992  (round-robin balances triangle lengths).
    #pragma unroll
    for (int m = 0; m < 32; ++m) {
        const int i = g + (m << 5);
        if (i < NDIM - 1) {
            const float* row = Sb + (size_t)i * NDIM + (i + 1);
            const int rem = NDIM - 1 - i;      // valid elements in this row
            int c = t;
            if (c < rem) { float v = row[c]; s0 += v; q0 += v * v; }
            c += 256;
            if (c < rem) { float v = row[c]; s1 += v; q1 += v * v; }
            c += 256;
            if (c < rem) { float v = row[c]; s2 += v; q2 += v * v; }
            c += 256;
            if (c < rem) { float v = row[c]; s3 += v; q3 += v * v; }
        }
    }

    float* psum = part + (size_t)blockIdx.x * (2 * NSEGP);
    float* psq  = psum + NSEGP;
    psum[t]       = s0;  psum[t + 256] = s1;
    psum[t + 512] = s2;  psum[t + 768] = s3;
    psq[t]        = q0;  psq[t + 256]  = q1;
    psq[t + 512]  = q2;  psq[t + 768]  = q3;
}

// ---------------------------------------------------------------------------
// Kernel 2: 128 blocks = 32 batches x 4 segment-chunks. One segment per
// thread; fully unrolled 32-way g reduction -> 64 outstanding coalesced
// loads per thread. Computes std_scaled and block-reduces to chunk partials.
// ---------------------------------------------------------------------------
__global__ __launch_bounds__(BLK) void reduce_kernel(
        const float* __restrict__ part,  // (BATCH*G, 2, NSEGP)
        float* __restrict__ cpart)       // (BATCH*CHUNKS)
{
    const int b = blockIdx.x >> 2;           // / CHUNKS
    const int c = blockIdx.x & (CHUNKS - 1); // % CHUNKS
    const int s = (c << 8) + threadIdx.x;    // segment index, 0..1023

    float acc = 0.f;
    if (s < NUSE) {
        float sum = 0.f, sq = 0.f;
        const float* p = part + (size_t)b * G * (2 * NSEGP) + s;
        #pragma unroll
        for (int g = 0; g < G; ++g) {
            sum += p[(size_t)g * (2 * NSEGP)];
            sq  += p[(size_t)g * (2 * NSEGP) + NSEGP];
        }
        float cnt  = (float)(NDIM - 1 - s);
        float mean = sum / cnt;
        float var  = (sq - cnt * mean * mean) / (cnt - 1.0f);
        acc = sqrtf(fmaxf(var, 0.0f)) * cnt * 0.05f;   // * cnt / 20
    }

    #pragma unroll
    for (int off = 32; off > 0; off >>= 1)
        acc += __shfl_down(acc, off, 64);

    __shared__ float wpart[BLK / 64];
    if ((threadIdx.x & 63) == 0) wpart[threadIdx.x >> 6] = acc;
    __syncthreads();
    if (threadIdx.x == 0) {
        float tsum = 0.f;
        #pragma unroll
        for (int k = 0; k < BLK / 64; ++k) tsum += wpart[k];
        cpart[blockIdx.x] = tsum;
    }
}

// ---------------------------------------------------------------------------
// Kernel 3: fold the 128 chunk partials -> scalar grand mean.
// ---------------------------------------------------------------------------
__global__ void final_kernel(const float* __restrict__ cpart,
                             float* __restrict__ out)
{
    float v = cpart[threadIdx.x] + cpart[threadIdx.x + 64];
    #pragma unroll
    for (int off = 32; off > 0; off >>= 1)
        v += __shfl_down(v, off, 64);
    if (threadIdx.x == 0)
        out[0] = v / (float)(BATCH * NUSE);
}

// ---------------------------------------------------------------------------
extern "C" void kernel_launch(void* const* d_in, const int* in_sizes, int n_in,
                              void* d_out, int out_size, void* d_ws, size_t ws_size,
                              hipStream_t stream) {
    const float* S = (const float*)d_in[0];
    float* out = (float*)d_out;

    float* part  = (float*)d_ws;                         // BATCH*G*2*NSEGP floats (8.4 MB)
    float* cpart = part + (size_t)BATCH * G * 2 * NSEGP; // BATCH*CHUNKS floats

    seg_partial_kernel<<<BATCH * G, BLK, 0, stream>>>(S, part);
    reduce_kernel<<<BATCH * CHUNKS, BLK, 0, stream>>>(part, cpart);
    final_kernel<<<1, 64, 0, stream>>>(cpart, out);
}

// Round 4
// 190.567 us; speedup vs baseline: 1.9337x; 1.1527x over previous
//
#include <hip/hip_runtime.h>
#include <hip/hip_bf16.h>

// Problem constants (match reference)
#define BATCH 32
#define NDIM  1024
#define NSEGP 1024          // padded segment slots per partial (1023 real)
#define NUSE  1022          // segments used in the mean (nseg - 1)
#define BLK   256
#define G     32            // row-groups per batch
#define RBLK  64            // reduce block = 1 wave

// 16-byte vector with only 4-byte alignment guarantee (row base shifts by i+1,
// so quads are dword-aligned but not always 16B-aligned). Compiler emits
// dwordx4 when legal, else splits -> never worse than 4 scalar loads.
typedef float f4a __attribute__((ext_vector_type(4), aligned(4)));
// Fully aligned 16-byte vector for the workspace (16B-aligned by construction).
typedef float f4  __attribute__((ext_vector_type(4), aligned(16)));

// ---------------------------------------------------------------------------
// Kernel 1: register-binned partial segment sums, quad ownership.
// Thread t owns segments {4t..4t+3}; for row i it reads columns
// i+1+4t .. i+1+4t+3 as ONE 16-byte load (s = j-i-1 is i-invariant).
// 32 independent loads/thread, branch only on the (coherent) row cutoff.
// HBM traffic = upper triangle only (masked lanes issue no requests).
// ---------------------------------------------------------------------------
__global__ __launch_bounds__(BLK) void seg_partial_kernel(
        const float* __restrict__ S,     // (BATCH, NDIM, NDIM)
        float* __restrict__ part)        // (BATCH*G, 2, NSEGP)
{
    const int b  = blockIdx.x >> 5;       // / G
    const int g  = blockIdx.x & (G - 1);  // % G
    const int c0 = threadIdx.x << 2;      // first owned segment

    float s0 = 0.f, s1 = 0.f, s2 = 0.f, s3 = 0.f;
    float q0 = 0.f, q1 = 0.f, q2 = 0.f, q3 = 0.f;

    const float* Sb = S + (size_t)b * NDIM * NDIM;

    // Rows i = g, g+32, ..., g+992 (round-robin balances triangle lengths).
    #pragma unroll
    for (int m = 0; m < 32; ++m) {
        const int i = g + (m << 5);
        if (i < NDIM - 1) {                  // uniform (false only g=31,m=31)
            const int rem = NDIM - 1 - i;    // valid elements in this row
            if (c0 < rem) {                  // coherent lane cutoff
                // In-bounds even for the tail quad: max flat index is
                // b*2^20 + 1022*1024 + 1023 + 1023 + 3 = b*2^20 + 1048574.
                f4a v = *(const f4a*)(Sb + (size_t)i * NDIM + (i + 1) + c0);
                float v0 = v.x;                            // c0 < rem holds
                float v1 = (c0 + 1 < rem) ? v.y : 0.f;     // tail masks
                float v2 = (c0 + 2 < rem) ? v.z : 0.f;
                float v3 = (c0 + 3 < rem) ? v.w : 0.f;
                s0 += v0; q0 += v0 * v0;
                s1 += v1; q1 += v1 * v1;
                s2 += v2; q2 += v2 * v2;
                s3 += v3; q3 += v3 * v3;
            }
        }
    }

    float* psum = part + (size_t)blockIdx.x * (2 * NSEGP);
    ((f4*)psum)[threadIdx.x]          = (f4){s0, s1, s2, s3};
    ((f4*)(psum + NSEGP))[threadIdx.x] = (f4){q0, q1, q2, q3};
}

// ---------------------------------------------------------------------------
// Kernel 2: 128 one-wave blocks = 32 batches x 4 segment-chunks. Thread t
// owns segment quad s = c*256 + 4t .. +3; 64 independent float4 loads
// (fully unrolled g reduction), finalize, wave-reduce. No LDS, no barrier.
// ---------------------------------------------------------------------------
__global__ __launch_bounds__(RBLK) void reduce_kernel(
        const float* __restrict__ part,  // (BATCH*G, 2, NSEGP)
        float* __restrict__ cpart)       // (BATCH*4)
{
    const int b  = blockIdx.x >> 2;
    const int c  = blockIdx.x & 3;
    const int t  = threadIdx.x;              // 0..63
    const int s0 = (c << 8) + (t << 2);      // quad base segment
    const int qi = s0 >> 2;                  // quad index within 1024 slots

    f4 sum = {0.f, 0.f, 0.f, 0.f};
    f4 sq  = {0.f, 0.f, 0.f, 0.f};
    const float* p = part + (size_t)b * G * (2 * NSEGP);
    #pragma unroll
    for (int g = 0; g < G; ++g) {
        f4 a = ((const f4*)(p + (size_t)g * (2 * NSEGP)))[qi];
        f4 z = ((const f4*)(p + (size_t)g * (2 * NSEGP) + NSEGP))[qi];
        sum += a;
        sq  += z;
    }

    float acc = 0.f;
    #pragma unroll
    for (int r = 0; r < 4; ++r) {
        const int s = s0 + r;
        if (s < NUSE) {
            float cnt  = (float)(NDIM - 1 - s);
            float mean = sum[r] / cnt;
            float var  = (sq[r] - cnt * mean * mean) / (cnt - 1.0f);
            acc += sqrtf(fmaxf(var, 0.0f)) * cnt * 0.05f;   // * cnt / 20
        }
    }

    #pragma unroll
    for (int off = 32; off > 0; off >>= 1)
        acc += __shfl_down(acc, off, 64);
    if (t == 0) cpart[blockIdx.x] = acc;
}

// ---------------------------------------------------------------------------
// Kernel 3: fold the 128 chunk partials -> scalar grand mean.
// ---------------------------------------------------------------------------
__global__ void final_kernel(const float* __restrict__ cpart,
                             float* __restrict__ out)
{
    float v = cpart[threadIdx.x] + cpart[threadIdx.x + 64];
    #pragma unroll
    for (int off = 32; off > 0; off >>= 1)
        v += __shfl_down(v, off, 64);
    if (threadIdx.x == 0)
        out[0] = v / (float)(BATCH * NUSE);
}

// ---------------------------------------------------------------------------
extern "C" void kernel_launch(void* const* d_in, const int* in_sizes, int n_in,
                              void* d_out, int out_size, void* d_ws, size_t ws_size,
                              hipStream_t stream) {
    const float* S = (const float*)d_in[0];
    float* out = (float*)d_out;

    float* part  = (float*)d_ws;                         // BATCH*G*2*NSEGP floats (8.4 MB)
    float* cpart = part + (size_t)BATCH * G * 2 * NSEGP; // 128 floats

    seg_partial_kernel<<<BATCH * G, BLK, 0, stream>>>(S, part);
    reduce_kernel<<<BATCH * 4, RBLK, 0, stream>>>(part, cpart);
    final_kernel<<<1, 64, 0, stream>>>(cpart, out);
}

// Round 5
// 183.981 us; speedup vs baseline: 2.0029x; 1.0358x over previous
//
#include <hip/hip_runtime.h>
#include <hip/hip_bf16.h>

// Problem constants (match reference)
#define BATCH 32
#define NDIM  1024
#define NSEGP 1024          // padded segment slots per partial (1023 real)
#define NUSE  1022          // segments used in the mean (nseg - 1)
#define BLK   256
#define G     64            // row-groups per batch (2048 blocks = 8/CU, 100% occ)
#define ROWS  16            // rows per block = NDIM/G
#define RBLK  64            // reduce block = 1 wave

// 16-byte vector with only 4-byte alignment guarantee (row base shifts by i+1,
// so quads are dword-aligned but not always 16B-aligned).
typedef float f4a __attribute__((ext_vector_type(4), aligned(4)));
// Fully aligned 16-byte vector for the workspace.
typedef float f4  __attribute__((ext_vector_type(4), aligned(16)));

// ---------------------------------------------------------------------------
// Kernel 1: register-binned partial segment sums, quad ownership.
// Thread t owns segments {4t..4t+3}; for row i it reads columns
// i+1+4t .. i+1+4t+3 as ONE 16-byte nontemporal load (s = j-i-1 is
// i-invariant). 16 independent loads/thread, 32 waves/CU for latency cover.
// ---------------------------------------------------------------------------
__global__ __launch_bounds__(BLK) void seg_partial_kernel(
        const float* __restrict__ S,     // (BATCH, NDIM, NDIM)
        float* __restrict__ part)        // (BATCH*G, 2, NSEGP)
{
    const int b  = blockIdx.x >> 6;       // / G
    const int g  = blockIdx.x & (G - 1);  // % G
    const int c0 = threadIdx.x << 2;      // first owned segment

    float s0 = 0.f, s1 = 0.f, s2 = 0.f, s3 = 0.f;
    float q0 = 0.f, q1 = 0.f, q2 = 0.f, q3 = 0.f;

    // Row i = g + 64m; element (i, i+1+c0) at flat offset i*1024 + i+1 + c0.
    // Per-m stride: 64*1024 + 64 = 65600 floats.
    const float* p = S + (size_t)b * NDIM * NDIM + (size_t)g * (NDIM + 1) + 1 + c0;

    #pragma unroll
    for (int m = 0; m < ROWS; ++m) {
        const int i = g + (m << 6);
        if (i < NDIM - 1) {                  // uniform (false only g=63,m=15)
            const int rem = NDIM - 1 - i;    // valid elements in this row
            if (c0 < rem) {                  // coherent lane cutoff
                // Tail quad stays in-bounds: max flat index within batch is
                // 1022*1024 + 1023 + 1020 + 3 = 1048574 < 2^20.
                f4a v = __builtin_nontemporal_load((const f4a*)p);
                float v0 = v.x;                            // c0 < rem holds
                float v1 = (c0 + 1 < rem) ? v.y : 0.f;     // tail masks
                float v2 = (c0 + 2 < rem) ? v.z : 0.f;
                float v3 = (c0 + 3 < rem) ? v.w : 0.f;
                s0 += v0; q0 += v0 * v0;
                s1 += v1; q1 += v1 * v1;
                s2 += v2; q2 += v2 * v2;
                s3 += v3; q3 += v3 * v3;
            }
        }
        p += 64 * NDIM + 64;                 // next row handled by this block
    }

    float* psum = part + (size_t)blockIdx.x * (2 * NSEGP);
    ((f4*)psum)[threadIdx.x]           = (f4){s0, s1, s2, s3};
    ((f4*)(psum + NSEGP))[threadIdx.x] = (f4){q0, q1, q2, q3};
}

// ---------------------------------------------------------------------------
// Kernel 2: 128 one-wave blocks = 32 batches x 4 segment-chunks. Thread t
// owns segment quad s = c*256 + 4t .. +3; fully unrolled 64-way g reduction
// (128 independent float4 loads), finalize, wave-reduce. No LDS, no barrier.
// ---------------------------------------------------------------------------
__global__ __launch_bounds__(RBLK) void reduce_kernel(
        const float* __restrict__ part,  // (BATCH*G, 2, NSEGP)
        float* __restrict__ cpart)       // (BATCH*4)
{
    const int b  = blockIdx.x >> 2;
    const int c  = blockIdx.x & 3;
    const int t  = threadIdx.x;              // 0..63
    const int s0 = (c << 8) + (t << 2);      // quad base segment
    const int qi = s0 >> 2;                  // quad index within 1024 slots

    f4 sum = {0.f, 0.f, 0.f, 0.f};
    f4 sq  = {0.f, 0.f, 0.f, 0.f};
    const float* p = part + (size_t)b * G * (2 * NSEGP);
    #pragma unroll
    for (int g = 0; g < G; ++g) {
        f4 a = ((const f4*)(p + (size_t)g * (2 * NSEGP)))[qi];
        f4 z = ((const f4*)(p + (size_t)g * (2 * NSEGP) + NSEGP))[qi];
        sum += a;
        sq  += z;
    }

    float acc = 0.f;
    #pragma unroll
    for (int r = 0; r < 4; ++r) {
        const int s = s0 + r;
        if (s < NUSE) {
            float cnt  = (float)(NDIM - 1 - s);
            float mean = sum[r] / cnt;
            float var  = (sq[r] - cnt * mean * mean) / (cnt - 1.0f);
            acc += sqrtf(fmaxf(var, 0.0f)) * cnt * 0.05f;   // * cnt / 20
        }
    }

    #pragma unroll
    for (int off = 32; off > 0; off >>= 1)
        acc += __shfl_down(acc, off, 64);
    if (t == 0) cpart[blockIdx.x] = acc;
}

// ---------------------------------------------------------------------------
// Kernel 3: fold the 128 chunk partials -> scalar grand mean.
// ---------------------------------------------------------------------------
__global__ void final_kernel(const float* __restrict__ cpart,
                             float* __restrict__ out)
{
    float v = cpart[threadIdx.x] + cpart[threadIdx.x + 64];
    #pragma unroll
    for (int off = 32; off > 0; off >>= 1)
        v += __shfl_down(v, off, 64);
    if (threadIdx.x == 0)
        out[0] = v / (float)(BATCH * NUSE);
}

// ---------------------------------------------------------------------------
extern "C" void kernel_launch(void* const* d_in, const int* in_sizes, int n_in,
                              void* d_out, int out_size, void* d_ws, size_t ws_size,
                              hipStream_t stream) {
    const float* S = (const float*)d_in[0];
    float* out = (float*)d_out;

    float* part  = (float*)d_ws;                         // BATCH*G*2*NSEGP floats (16.8 MB)
    float* cpart = part + (size_t)BATCH * G * 2 * NSEGP; // 128 floats

    seg_partial_kernel<<<BATCH * G, BLK, 0, stream>>>(S, part);
    reduce_kernel<<<BATCH * 4, RBLK, 0, stream>>>(part, cpart);
    final_kernel<<<1, 64, 0, stream>>>(cpart, out);
}